// Round 1
// baseline (426.786 us; speedup 1.0000x reference)
//
#include <hip/hip_runtime.h>
#include <math.h>

#define S_LEN 2048
#define D_MODEL 1024
#define NH 16
#define DK 64
#define BATCH 4

// log2(10000)/64
#define ROPE_L2F 0.20762050593046014f
// 0.125 * log2(e): folds 1/sqrt(dk) and exp->exp2 conversion into Q
#define QSCALE 0.18033688011112042f

typedef __attribute__((ext_vector_type(8))) short bf16x8;
typedef __attribute__((ext_vector_type(4))) short short4v;
typedef __attribute__((ext_vector_type(2))) short short2v;
typedef __attribute__((ext_vector_type(4))) float f32x4;

__device__ inline short f2bf(float f) {            // RNE fp32 -> bf16 bits
    unsigned u = __builtin_bit_cast(unsigned, f);
    unsigned r = u + 0x7FFFu + ((u >> 16) & 1u);
    return (short)(r >> 16);
}

// async global->LDS, 16B per lane; lds base must be wave-uniform.
__device__ inline void load_lds16(const void* g, void* l) {
    __builtin_amdgcn_global_load_lds(
        (const __attribute__((address_space(1))) unsigned int*)g,
        (__attribute__((address_space(3))) unsigned int*)l, 16, 0, 0);
}

// ---------------------------------------------------------------------------
// One-time fp32 -> bf16 conversions.
// ---------------------------------------------------------------------------
__global__ __launch_bounds__(256) void conv_bf16(
    const float* __restrict__ src, short* __restrict__ dst, int n)
{
    int i = (blockIdx.x * 256 + threadIdx.x) * 8;
    if (i >= n) return;
    float4 a = *(const float4*)&src[i];
    float4 b = *(const float4*)&src[i + 4];
    short h[8] = { f2bf(a.x), f2bf(a.y), f2bf(a.z), f2bf(a.w),
                   f2bf(b.x), f2bf(b.y), f2bf(b.z), f2bf(b.w) };
    *(bf16x8*)&dst[i] = *(bf16x8*)h;
}

__global__ __launch_bounds__(256) void conv_w4(
    const float* __restrict__ Wq, const float* __restrict__ Wk,
    const float* __restrict__ Wv, const float* __restrict__ Wo,
    short* __restrict__ dst)
{
    const float* srcs[4] = { Wq, Wk, Wv, Wo };
    const float* s = srcs[blockIdx.y];
    short* d = dst + (size_t)blockIdx.y * (D_MODEL * D_MODEL);
    int i = (blockIdx.x * 256 + threadIdx.x) * 8;
    float4 a = *(const float4*)&s[i];
    float4 b = *(const float4*)&s[i + 4];
    short h[8] = { f2bf(a.x), f2bf(a.y), f2bf(a.z), f2bf(a.w),
                   f2bf(b.x), f2bf(b.y), f2bf(b.z), f2bf(b.w) };
    *(bf16x8*)&d[i] = *(bf16x8*)h;
}

// ---------------------------------------------------------------------------
// RoPE cos/sin table: cst[si*32 + f] = (cos, sin) of tp[si] * theta^(-2f/64).
// 2048*32 float2 = 512 KB, computed once; removes exp2f+__sincosf from the
// 16M-element Q/K projection epilogues (trans-pipe pressure -> one L2 load).
// ---------------------------------------------------------------------------
__global__ __launch_bounds__(256) void rope_tab(
    const int* __restrict__ tp, float2* __restrict__ cst)
{
    int idx = blockIdx.x * 256 + threadIdx.x;      // 65536 entries
    int si = idx >> 5;
    int f  = idx & 31;
    float pos = (float)tp[si];
    float freq = exp2f(-(float)(2 * f) * ROPE_L2F);
    float s, c;
    __sincosf(pos * freq, &s, &c);
    cst[idx] = make_float2(c, s);
}

// ---------------------------------------------------------------------------
// bf16 MFMA GEMM main loop (m97-style): 128x128 tile, BK=32, 4 waves 2x2.
// A/B tiles staged via global_load_lds (16B/lane, async). LDS unpadded
// [128][32] shorts; 16B chunks XOR-swizzled (phys = chunk ^ (row&3)) so frag
// ds_read_b128 is <=4-way. Shared between proj_qkv and proj_out.
// ---------------------------------------------------------------------------
#define PROJ_PROLOGUE()                                                      \
    __shared__ short As[128][32];                                            \
    __shared__ short Bs[128][32];                                            \
    const int m0 = blockIdx.y * 128;                                         \
    const int n0 = blockIdx.x * 128;                                         \
    const int tid = threadIdx.x;                                             \
    const int lane = tid & 63;                                               \
    const int wave = tid >> 6;                                               \
    const int quad = lane >> 4;                                              \
    const int l16 = lane & 15;                                               \
    const int wr = (wave >> 1) * 64;                                         \
    const int wc = (wave & 1) * 64;                                          \
    const int srow = wave * 32 + (lane >> 2);                                \
    const int schunk = (lane & 3) ^ ((lane >> 2) & 3);                       \
    const short* agp = &A[(size_t)(m0 + srow) * D_MODEL + schunk * 8];       \
    const short* bgp = &Bw[(size_t)(n0 + srow) * D_MODEL + schunk * 8];      \
    short* alds0 = &As[wave * 32][0];                                        \
    short* alds1 = &As[wave * 32 + 16][0];                                   \
    short* blds0 = &Bs[wave * 32][0];                                        \
    short* blds1 = &Bs[wave * 32 + 16][0];                                   \
    const int fchunk = quad ^ (l16 & 3);                                     \
    f32x4 acc[4][4] = {};                                                    \
    for (int k0 = 0; k0 < D_MODEL; k0 += 32) {                               \
        load_lds16(agp, alds0);                                              \
        load_lds16(agp + 16 * D_MODEL, alds1);                               \
        load_lds16(bgp, blds0);                                              \
        load_lds16(bgp + 16 * D_MODEL, blds1);                               \
        agp += 32; bgp += 32;                                                \
        __syncthreads();                                                     \
        bf16x8 a_h[4], b_h[4];                                               \
        _Pragma("unroll")                                                    \
        for (int t = 0; t < 4; ++t) {                                        \
            a_h[t] = *(const bf16x8*)&As[wr + t * 16 + l16][fchunk * 8];     \
            b_h[t] = *(const bf16x8*)&Bs[wc + t * 16 + l16][fchunk * 8];     \
        }                                                                    \
        _Pragma("unroll")                                                    \
        for (int mt = 0; mt < 4; ++mt)                                       \
            _Pragma("unroll")                                                \
            for (int nt = 0; nt < 4; ++nt)                                   \
                acc[mt][nt] = __builtin_amdgcn_mfma_f32_16x16x32_bf16(       \
                    a_h[mt], b_h[nt], acc[mt][nt], 0, 0, 0);                 \
        __syncthreads();                                                     \
    }

// ---------------------------------------------------------------------------
// Fused QKV projection: C = x (8192x1024) @ [Wq;Wk;Wv]^T (1024x3072).
// grid (24, 64) = 1536 blocks (vs 3x512 before). n0>>10 selects Q/K/V
// (block-uniform: 128-col blocks never straddle a 1024 boundary).
// Q/K epilogue applies RoPE from the precomputed table; Q folds QSCALE.
// Output layout (b, h, s, dk) bf16.
// ---------------------------------------------------------------------------
__global__ __launch_bounds__(256) void proj_qkv(
    const short* __restrict__ A, const short* __restrict__ Bw,
    const float2* __restrict__ cst,
    short* __restrict__ Qo, short* __restrict__ Ko, short* __restrict__ Vo)
{
    PROJ_PROLOGUE()

    const int which = n0 >> 10;                    // 0=Q 1=K 2=V
    short* __restrict__ outp = (which == 0) ? Qo : (which == 1) ? Ko : Vo;
    const float scale = (which == 0) ? QSCALE : 1.0f;
    const int nbase = n0 & (D_MODEL - 1);

#pragma unroll
    for (int mt = 0; mt < 4; ++mt) {
#pragma unroll
        for (int r = 0; r < 4; ++r) {
            const int row = m0 + wr + mt * 16 + quad * 4 + r;
            const int bi = row >> 11;
            const int si = row & (S_LEN - 1);
#pragma unroll
            for (int nt = 0; nt < 4; ++nt) {
                const int col = nbase + wc + nt * 16 + l16;
                const int head = col >> 6;
                const int tloc = col & 63;
                float v = acc[mt][nt][r];
                float res;
                if (which < 2) {
                    float partner = __shfl_xor(v, 1);
                    float xe = (lane & 1) ? partner : v;
                    float xo = (lane & 1) ? v : partner;
                    float2 cs = cst[si * 32 + (tloc >> 1)];
                    res = ((lane & 1) ? (cs.y * xe + cs.x * xo)
                                      : (cs.x * xe - cs.y * xo)) * scale;
                } else {
                    res = v;
                }
                outp[(((size_t)bi * NH + head) * S_LEN + si) * DK + tloc] =
                    f2bf(res);
            }
        }
    }
}

// ---------------------------------------------------------------------------
// Output projection: out = attnO (8192x1024) @ Wo^T, fp32 row-major.
// ---------------------------------------------------------------------------
__global__ __launch_bounds__(256) void proj_out(
    const short* __restrict__ A, const short* __restrict__ Bw,
    float* __restrict__ outf)
{
    PROJ_PROLOGUE()

#pragma unroll
    for (int mt = 0; mt < 4; ++mt) {
#pragma unroll
        for (int r = 0; r < 4; ++r) {
            const int row = m0 + wr + mt * 16 + quad * 4 + r;
#pragma unroll
            for (int nt = 0; nt < 4; ++nt) {
                int col = n0 + wc + nt * 16 + l16;
                outf[(size_t)row * D_MODEL + col] = acc[mt][nt][r];
            }
        }
    }
}

// ---------------------------------------------------------------------------
// MFMA flash causal attention, software-pipelined.
// Bq=128 (4 waves x 32 q rows), Bk=64. S^T = K*Q^T, O^T = V^T*P^T (q rides
// lane&15; softmax per-lane + 2 shfl). Vt double-buffered => ONE barrier
// per k-tile; next tile's K frags and V tile prefetched into registers
// during current tile's compute. s_setprio(1) wraps the MFMA clusters (T5:
// waves here are at divergent phases, the regime where it measured +4-7%).
// ---------------------------------------------------------------------------
#define PADS 72

__global__ __launch_bounds__(256) void attn_bf16(
    const short* __restrict__ Q, const short* __restrict__ K,
    const short* __restrict__ V, short* __restrict__ O)
{
    __shared__ short Vt[2][64][PADS];  // V tile transposed [d][k], dbuf
    __shared__ short Ps[128][PADS];    // P rows, wave-private

    const int bh = blockIdx.y;
    const int bx = (gridDim.x - 1) - blockIdx.x;   // heavy blocks first
    const int q0 = bx * 128;
    const int tid = threadIdx.x;
    const int wave = tid >> 6;
    const int lane = tid & 63;
    const int quad = lane >> 4;
    const int l16 = lane & 15;
    const int qbase = q0 + wave * 32;

    const short* Kb = K + (size_t)bh * S_LEN * DK;
    const short* Vb = V + (size_t)bh * S_LEN * DK;

    // Q fragments straight from global (wave-private rows)
    bf16x8 Qf[2][2];
#pragma unroll
    for (int sub = 0; sub < 2; ++sub)
#pragma unroll
        for (int c = 0; c < 2; ++c)
            Qf[sub][c] = *(const bf16x8*)
                &Q[((size_t)bh * S_LEN + qbase + sub * 16 + l16) * DK +
                   c * 32 + quad * 8];

    // V staging geometry (transpose via short2)
    const int kp2 = (tid & 31) * 2;
    const int db = (tid >> 5) * 8;

    // preload tile 0: V into regs, K frags into regs
    bf16x8 v0 = *(const bf16x8*)&Vb[(size_t)kp2 * DK + db];
    bf16x8 v1 = *(const bf16x8*)&Vb[(size_t)(kp2 + 1) * DK + db];
    bf16x8 Kf[4][2];
#pragma unroll
    for (int kt = 0; kt < 4; ++kt)
#pragma unroll
        for (int c = 0; c < 2; ++c)
            Kf[kt][c] = *(const bf16x8*)
                &Kb[(size_t)(kt * 16 + l16) * DK + c * 32 + quad * 8];

    float m_i[2] = { -1e30f, -1e30f }, l_i[2] = { 0.0f, 0.0f };
    f32x4 o[2][4] = {};

    const int ktiles = 2 * bx + 2;
    for (int t = 0; t < ktiles; ++t) {
        const int k0 = t * 64;
        const int buf = t & 1;
        // ---- commit prefetched V regs to Vt[buf] ----
#pragma unroll
        for (int i = 0; i < 8; ++i) {
            short2v p; p.x = v0[i]; p.y = v1[i];
            *(short2v*)&Vt[buf][db + i][kp2] = p;
        }
        __syncthreads();   // single barrier per tile (dbuf makes it safe)

        // ---- prefetch tile t+1 (V regs; K frags if this wave needs it) ----
        if (t + 1 < ktiles) {
            const short* vp = &Vb[(size_t)((t + 1) * 64 + kp2) * DK + db];
            v0 = *(const bf16x8*)vp;
            v1 = *(const bf16x8*)(vp + DK);
        }
        bf16x8 Kn[4][2];
        const bool need_next = (t + 1 < ktiles) && ((t + 1) * 64 <= qbase + 31);
        if (need_next) {
#pragma unroll
            for (int kt = 0; kt < 4; ++kt)
#pragma unroll
                for (int c = 0; c < 2; ++c)
                    Kn[kt][c] = *(const bf16x8*)
                        &Kb[(size_t)(k0 + 64 + kt * 16 + l16) * DK +
                            c * 32 + quad * 8];
        }

        if (k0 <= qbase + 31) {      // wave has live q rows for this tile
#pragma unroll
            for (int sub = 0; sub < 2; ++sub) {
                f32x4 sT[4] = {};
                __builtin_amdgcn_s_setprio(1);
#pragma unroll
                for (int c = 0; c < 2; ++c)
#pragma unroll
                    for (int kt = 0; kt < 4; ++kt)
                        sT[kt] = __builtin_amdgcn_mfma_f32_16x16x32_bf16(
                            Kf[kt][c], Qf[sub][c], sT[kt], 0, 0, 0);
                __builtin_amdgcn_s_setprio(0);

                const int qg = qbase + sub * 16 + l16;
                if (k0 + 63 > qbase + sub * 16) {   // causal mask needed
#pragma unroll
                    for (int kt = 0; kt < 4; ++kt)
#pragma unroll
                        for (int r = 0; r < 4; ++r)
                            if (k0 + kt * 16 + quad * 4 + r > qg)
                                sT[kt][r] = -1e30f;
                }

                // online softmax, exp2 domain, per-lane state
                float tmax = -1e30f;
#pragma unroll
                for (int kt = 0; kt < 4; ++kt)
#pragma unroll
                    for (int r = 0; r < 4; ++r)
                        tmax = fmaxf(tmax, sT[kt][r]);
                tmax = fmaxf(tmax, __shfl_xor(tmax, 16));
                tmax = fmaxf(tmax, __shfl_xor(tmax, 32));
                float mn = fmaxf(m_i[sub], tmax);
                float alpha = exp2f(m_i[sub] - mn);
                m_i[sub] = mn;
                float rs = 0.0f;
                const int prow = wave * 32 + sub * 16 + l16;
#pragma unroll
                for (int kt = 0; kt < 4; ++kt) {
                    float p0 = exp2f(sT[kt][0] - mn);
                    float p1 = exp2f(sT[kt][1] - mn);
                    float p2 = exp2f(sT[kt][2] - mn);
                    float p3 = exp2f(sT[kt][3] - mn);
                    rs += (p0 + p1) + (p2 + p3);
                    short4v pk;
                    pk.x = f2bf(p0); pk.y = f2bf(p1);
                    pk.z = f2bf(p2); pk.w = f2bf(p3);
                    *(short4v*)&Ps[prow][kt * 16 + quad * 4] = pk;
                }
                rs += __shfl_xor(rs, 16);
                rs += __shfl_xor(rs, 32);
                l_i[sub] = l_i[sub] * alpha + rs;
#pragma unroll
                for (int dt = 0; dt < 4; ++dt) {
                    o[sub][dt][0] *= alpha; o[sub][dt][1] *= alpha;
                    o[sub][dt][2] *= alpha; o[sub][dt][3] *= alpha;
                }
            }

            // ---- O^T += V^T P^T ----
            bf16x8 Pf[2][2];
#pragma unroll
            for (int sub = 0; sub < 2; ++sub)
#pragma unroll
                for (int c = 0; c < 2; ++c)
                    Pf[sub][c] = *(const bf16x8*)
                        &Ps[wave * 32 + sub * 16 + l16][c * 32 + quad * 8];
            __builtin_amdgcn_s_setprio(1);
#pragma unroll
            for (int c = 0; c < 2; ++c)
#pragma unroll
                for (int dt = 0; dt < 4; ++dt) {
                    bf16x8 av = *(const bf16x8*)
                        &Vt[buf][dt * 16 + l16][c * 32 + quad * 8];
#pragma unroll
                    for (int sub = 0; sub < 2; ++sub)
                        o[sub][dt] = __builtin_amdgcn_mfma_f32_16x16x32_bf16(
                            av, Pf[sub][c], o[sub][dt], 0, 0, 0);
                }
            __builtin_amdgcn_s_setprio(0);
        }

        if (need_next) {
#pragma unroll
            for (int kt = 0; kt < 4; ++kt)
#pragma unroll
                for (int c = 0; c < 2; ++c)
                    Kf[kt][c] = Kn[kt][c];
        }
    }

    // ---- epilogue: normalize, write bf16 (b, s, d) ----
    const int bi = bh >> 4;
    const int head = bh & 15;
#pragma unroll
    for (int sub = 0; sub < 2; ++sub) {
        const int q = qbase + sub * 16 + l16;
        const float linv = 1.0f / l_i[sub];
        short* ob = &O[((size_t)bi * S_LEN + q) * D_MODEL + head * DK];
#pragma unroll
        for (int dt = 0; dt < 4; ++dt) {
            short4v h;
            h.x = f2bf(o[sub][dt][0] * linv);
            h.y = f2bf(o[sub][dt][1] * linv);
            h.z = f2bf(o[sub][dt][2] * linv);
            h.w = f2bf(o[sub][dt][3] * linv);
            *(short4v*)&ob[dt * 16 + quad * 4] = h;
        }
    }
}

extern "C" void kernel_launch(void* const* d_in, const int* in_sizes, int n_in,
                              void* d_out, int out_size, void* d_ws, size_t ws_size,
                              hipStream_t stream) {
    const float* x  = (const float*)d_in[0];
    const float* Wq = (const float*)d_in[1];
    const float* Wk = (const float*)d_in[2];
    const float* Wv = (const float*)d_in[3];
    const float* Wo = (const float*)d_in[4];
    const int*   tp = (const int*)d_in[5];
    float* out = (float*)d_out;

    const int n  = BATCH * S_LEN * D_MODEL;       // 8388608
    const int nw = D_MODEL * D_MODEL;             // 1048576
    short* sw   = (short*)d_ws;
    short* xbf  = sw;
    short* Qbf  = sw + (size_t)n;
    short* Kbf  = sw + (size_t)2 * n;
    short* Vbf  = sw + (size_t)3 * n;
    short* Obf  = sw + (size_t)4 * n;
    short* Wqbf = sw + (size_t)5 * n;             // Wq;Wk;Wv contiguous (3072x1024)
    short* Wobf = Wqbf + (size_t)3 * nw;
    // RoPE table overlaid on Obf (dead until attn writes it; stream order
    // guarantees rope_tab -> proj_qkv(read) -> attn(overwrite) -> proj_out).
    float2* cst = (float2*)Obf;                   // 512 KB of the 16.8 MB region

    dim3 blk(256);
    conv_bf16<<<n / (256 * 8), blk, 0, stream>>>(x, xbf, n);
    dim3 gw(nw / (256 * 8), 4);
    conv_w4<<<gw, blk, 0, stream>>>(Wq, Wk, Wv, Wo, Wqbf);
    rope_tab<<<(S_LEN * 32) / 256, blk, 0, stream>>>(tp, cst);

    dim3 gqkv(3 * D_MODEL / 128, (BATCH * S_LEN) / 128);   // (24, 64)
    proj_qkv<<<gqkv, blk, 0, stream>>>(xbf, Wqbf, cst, Qbf, Kbf, Vbf);

    dim3 gattn(S_LEN / 128, BATCH * NH);                   // (16, 64)
    attn_bf16<<<gattn, blk, 0, stream>>>(Qbf, Kbf, Vbf, Obf);

    dim3 gout(D_MODEL / 128, (BATCH * S_LEN) / 128);       // (8, 64)
    proj_out<<<gout, blk, 0, stream>>>(Obf, Wobf, out);
}

// Round 3
// 413.103 us; speedup vs baseline: 1.0331x; 1.0331x over previous
//
#include <hip/hip_runtime.h>
#include <math.h>

#define S_LEN 2048
#define D_MODEL 1024
#define NH 16
#define DK 64
#define BATCH 4

// log2(10000)/64
#define ROPE_L2F 0.20762050593046014f
// 0.125 * log2(e): folds 1/sqrt(dk) and exp->exp2 conversion into Q
#define QSCALE 0.18033688011112042f

typedef __attribute__((ext_vector_type(8))) short bf16x8;
typedef __attribute__((ext_vector_type(4))) short short4v;
typedef __attribute__((ext_vector_type(2))) short short2v;
typedef __attribute__((ext_vector_type(4))) float f32x4;

__device__ inline short f2bf(float f) {            // RNE fp32 -> bf16 bits
    unsigned u = __builtin_bit_cast(unsigned, f);
    unsigned r = u + 0x7FFFu + ((u >> 16) & 1u);
    return (short)(r >> 16);
}

// packed fp32x2 -> bf16x2 (RNE), single VALU op
__device__ inline unsigned cvt_pk_bf16(float lo, float hi) {
    unsigned r;
    asm("v_cvt_pk_bf16_f32 %0, %1, %2" : "=v"(r) : "v"(lo), "v"(hi));
    return r;
}

// async global->LDS, 16B per lane; lds base must be wave-uniform.
__device__ inline void load_lds16(const void* g, void* l) {
    __builtin_amdgcn_global_load_lds(
        (const __attribute__((address_space(1))) unsigned int*)g,
        (__attribute__((address_space(3))) unsigned int*)l, 16, 0, 0);
}

// ---------------------------------------------------------------------------
// One-time fp32 -> bf16 conversions.
// ---------------------------------------------------------------------------
__global__ __launch_bounds__(256) void conv_bf16(
    const float* __restrict__ src, short* __restrict__ dst, int n)
{
    int i = (blockIdx.x * 256 + threadIdx.x) * 8;
    if (i >= n) return;
    float4 a = *(const float4*)&src[i];
    float4 b = *(const float4*)&src[i + 4];
    short h[8] = { f2bf(a.x), f2bf(a.y), f2bf(a.z), f2bf(a.w),
                   f2bf(b.x), f2bf(b.y), f2bf(b.z), f2bf(b.w) };
    *(bf16x8*)&dst[i] = *(bf16x8*)h;
}

__global__ __launch_bounds__(256) void conv_w4(
    const float* __restrict__ Wq, const float* __restrict__ Wk,
    const float* __restrict__ Wv, const float* __restrict__ Wo,
    short* __restrict__ dst)
{
    const float* srcs[4] = { Wq, Wk, Wv, Wo };
    const float* s = srcs[blockIdx.y];
    short* d = dst + (size_t)blockIdx.y * (D_MODEL * D_MODEL);
    int i = (blockIdx.x * 256 + threadIdx.x) * 8;
    float4 a = *(const float4*)&s[i];
    float4 b = *(const float4*)&s[i + 4];
    short h[8] = { f2bf(a.x), f2bf(a.y), f2bf(a.z), f2bf(a.w),
                   f2bf(b.x), f2bf(b.y), f2bf(b.z), f2bf(b.w) };
    *(bf16x8*)&d[i] = *(bf16x8*)h;
}

// ---------------------------------------------------------------------------
// RoPE cos/sin table: cst[si*32 + f] = (cos, sin) of tp[si] * theta^(-2f/64).
// ---------------------------------------------------------------------------
__global__ __launch_bounds__(256) void rope_tab(
    const int* __restrict__ tp, float2* __restrict__ cst)
{
    int idx = blockIdx.x * 256 + threadIdx.x;      // 65536 entries
    int si = idx >> 5;
    int f  = idx & 31;
    float pos = (float)tp[si];
    float freq = exp2f(-(float)(2 * f) * ROPE_L2F);
    float s, c;
    __sincosf(pos * freq, &s, &c);
    cst[idx] = make_float2(c, s);
}

// ---------------------------------------------------------------------------
// bf16 MFMA GEMM main loop (m97-style): 128x128 tile, BK=32, 4 waves 2x2.
// A/B tiles staged via global_load_lds (16B/lane, async). LDS unpadded
// [128][32] shorts; 16B chunks XOR-swizzled (phys = chunk ^ (row&3)) so frag
// ds_read_b128 is <=4-way. Shared between proj_qkv and proj_out.
// ---------------------------------------------------------------------------
#define PROJ_PROLOGUE()                                                      \
    __shared__ short As[128][32];                                            \
    __shared__ short Bs[128][32];                                            \
    const int m0 = blockIdx.y * 128;                                         \
    const int n0 = blockIdx.x * 128;                                         \
    const int tid = threadIdx.x;                                             \
    const int lane = tid & 63;                                               \
    const int wave = tid >> 6;                                               \
    const int quad = lane >> 4;                                              \
    const int l16 = lane & 15;                                               \
    const int wr = (wave >> 1) * 64;                                         \
    const int wc = (wave & 1) * 64;                                          \
    const int srow = wave * 32 + (lane >> 2);                                \
    const int schunk = (lane & 3) ^ ((lane >> 2) & 3);                       \
    const short* agp = &A[(size_t)(m0 + srow) * D_MODEL + schunk * 8];       \
    const short* bgp = &Bw[(size_t)(n0 + srow) * D_MODEL + schunk * 8];      \
    short* alds0 = &As[wave * 32][0];                                        \
    short* alds1 = &As[wave * 32 + 16][0];                                   \
    short* blds0 = &Bs[wave * 32][0];                                        \
    short* blds1 = &Bs[wave * 32 + 16][0];                                   \
    const int fchunk = quad ^ (l16 & 3);                                     \
    f32x4 acc[4][4] = {};                                                    \
    for (int k0 = 0; k0 < D_MODEL; k0 += 32) {                               \
        load_lds16(agp, alds0);                                              \
        load_lds16(agp + 16 * D_MODEL, alds1);                               \
        load_lds16(bgp, blds0);                                              \
        load_lds16(bgp + 16 * D_MODEL, blds1);                               \
        agp += 32; bgp += 32;                                                \
        __syncthreads();                                                     \
        bf16x8 a_h[4], b_h[4];                                               \
        _Pragma("unroll")                                                    \
        for (int t = 0; t < 4; ++t) {                                        \
            a_h[t] = *(const bf16x8*)&As[wr + t * 16 + l16][fchunk * 8];     \
            b_h[t] = *(const bf16x8*)&Bs[wc + t * 16 + l16][fchunk * 8];     \
        }                                                                    \
        _Pragma("unroll")                                                    \
        for (int mt = 0; mt < 4; ++mt)                                       \
            _Pragma("unroll")                                                \
            for (int nt = 0; nt < 4; ++nt)                                   \
                acc[mt][nt] = __builtin_amdgcn_mfma_f32_16x16x32_bf16(       \
                    a_h[mt], b_h[nt], acc[mt][nt], 0, 0, 0);                 \
        __syncthreads();                                                     \
    }

// ---------------------------------------------------------------------------
// Fused QKV projection: C = x (8192x1024) @ [Wq;Wk;Wv]^T (1024x3072).
// ---------------------------------------------------------------------------
__global__ __launch_bounds__(256) void proj_qkv(
    const short* __restrict__ A, const short* __restrict__ Bw,
    const float2* __restrict__ cst,
    short* __restrict__ Qo, short* __restrict__ Ko, short* __restrict__ Vo)
{
    PROJ_PROLOGUE()

    const int which = n0 >> 10;                    // 0=Q 1=K 2=V
    short* __restrict__ outp = (which == 0) ? Qo : (which == 1) ? Ko : Vo;
    const float scale = (which == 0) ? QSCALE : 1.0f;
    const int nbase = n0 & (D_MODEL - 1);

#pragma unroll
    for (int mt = 0; mt < 4; ++mt) {
#pragma unroll
        for (int r = 0; r < 4; ++r) {
            const int row = m0 + wr + mt * 16 + quad * 4 + r;
            const int bi = row >> 11;
            const int si = row & (S_LEN - 1);
#pragma unroll
            for (int nt = 0; nt < 4; ++nt) {
                const int col = nbase + wc + nt * 16 + l16;
                const int head = col >> 6;
                const int tloc = col & 63;
                float v = acc[mt][nt][r];
                float res;
                if (which < 2) {
                    float partner = __shfl_xor(v, 1);
                    float xe = (lane & 1) ? partner : v;
                    float xo = (lane & 1) ? v : partner;
                    float2 cs = cst[si * 32 + (tloc >> 1)];
                    res = ((lane & 1) ? (cs.y * xe + cs.x * xo)
                                      : (cs.x * xe - cs.y * xo)) * scale;
                } else {
                    res = v;
                }
                outp[(((size_t)bi * NH + head) * S_LEN + si) * DK + tloc] =
                    f2bf(res);
            }
        }
    }
}

// ---------------------------------------------------------------------------
// Output projection: out = attnO (8192x1024) @ Wo^T, fp32 row-major.
// ---------------------------------------------------------------------------
__global__ __launch_bounds__(256) void proj_out(
    const short* __restrict__ A, const short* __restrict__ Bw,
    float* __restrict__ outf)
{
    PROJ_PROLOGUE()

#pragma unroll
    for (int mt = 0; mt < 4; ++mt) {
#pragma unroll
        for (int r = 0; r < 4; ++r) {
            const int row = m0 + wr + mt * 16 + quad * 4 + r;
#pragma unroll
            for (int nt = 0; nt < 4; ++nt) {
                int col = n0 + wc + nt * 16 + l16;
                outf[(size_t)row * D_MODEL + col] = acc[mt][nt][r];
            }
        }
    }
}

// ---------------------------------------------------------------------------
// MFMA flash causal attention.
// Balanced pairing: grid (8, 64); each block runs q-tile (15-pair) THEN
// q-tile (pair) => every block does exactly 34 k-tiles (no straggler tail;
// old variable-ktiles grid averaged 11% occupancy). XCD grouping: with rr
// block->XCD dispatch, blockIdx.x == XCD, so each XCD owns 8 consecutive
// heads; per-XCD K/V working set = 8 x 512KB = 4MB = its L2 (cuts HBM
// re-fetch of K/V, was 110MB vs 48MB ideal).
// Per tile: S^T = K*Q^T, online softmax per-lane (+2 shfl), O^T += V^T*P^T.
// Vt double-buffered => one barrier/tile; V regs + K frags prefetched.
// Defer-max (T13, THR=8): O-rescale only when tile max grows past m+8
// (~once per q-tile). P packed via v_cvt_pk_bf16_f32 (1 op per 2 values).
// No setprio: 4-wave lockstep barriers = m190's null/negative regime.
// ktiles is always even => each half ends on buf=1, so the next half's
// buf=0 write never races the previous half's last reads.
// ---------------------------------------------------------------------------
#define PADS 72

__global__ __launch_bounds__(256) void attn_bf16(
    const short* __restrict__ Q, const short* __restrict__ K,
    const short* __restrict__ V, short* __restrict__ O)
{
    __shared__ short Vt[2][64][PADS];  // V tile transposed [d][k], dbuf
    __shared__ short Ps[128][PADS];    // P rows, wave-private

    const int bh   = blockIdx.x * 8 + (blockIdx.y >> 3);
    const int pair = blockIdx.y & 7;

    const int tid = threadIdx.x;
    const int wave = tid >> 6;
    const int lane = tid & 63;
    const int quad = lane >> 4;
    const int l16 = lane & 15;

    const short* Kb = K + (size_t)bh * S_LEN * DK;
    const short* Vb = V + (size_t)bh * S_LEN * DK;

    // V staging geometry (transpose via short2)
    const int kp2 = (tid & 31) * 2;
    const int db = (tid >> 5) * 8;

    const int bi = bh >> 4;
    const int head = bh & 15;

    for (int half = 0; half < 2; ++half) {
        const int bx = half ? pair : (15 - pair);
        const int qbase = bx * 128 + wave * 32;

        // Q fragments straight from global (wave-private rows)
        bf16x8 Qf[2][2];
#pragma unroll
        for (int sub = 0; sub < 2; ++sub)
#pragma unroll
            for (int c = 0; c < 2; ++c)
                Qf[sub][c] = *(const bf16x8*)
                    &Q[((size_t)bh * S_LEN + qbase + sub * 16 + l16) * DK +
                       c * 32 + quad * 8];

        // preload tile 0: V into regs, K frags into regs
        bf16x8 v0 = *(const bf16x8*)&Vb[(size_t)kp2 * DK + db];
        bf16x8 v1 = *(const bf16x8*)&Vb[(size_t)(kp2 + 1) * DK + db];
        bf16x8 Kf[4][2];
#pragma unroll
        for (int kt = 0; kt < 4; ++kt)
#pragma unroll
            for (int c = 0; c < 2; ++c)
                Kf[kt][c] = *(const bf16x8*)
                    &Kb[(size_t)(kt * 16 + l16) * DK + c * 32 + quad * 8];

        float m_i[2] = { -1e30f, -1e30f }, l_i[2] = { 0.0f, 0.0f };
        f32x4 o[2][4] = {};

        const int ktiles = 2 * bx + 2;
        for (int t = 0; t < ktiles; ++t) {
            const int k0 = t * 64;
            const int buf = t & 1;
            // ---- commit prefetched V regs to Vt[buf] ----
#pragma unroll
            for (int i = 0; i < 8; ++i) {
                short2v p; p.x = v0[i]; p.y = v1[i];
                *(short2v*)&Vt[buf][db + i][kp2] = p;
            }
            __syncthreads();   // single barrier per tile (dbuf makes it safe)

            // ---- prefetch tile t+1 ----
            if (t + 1 < ktiles) {
                const short* vp = &Vb[(size_t)((t + 1) * 64 + kp2) * DK + db];
                v0 = *(const bf16x8*)vp;
                v1 = *(const bf16x8*)(vp + DK);
            }
            bf16x8 Kn[4][2];
            const bool need_next =
                (t + 1 < ktiles) && ((t + 1) * 64 <= qbase + 31);
            if (need_next) {
#pragma unroll
                for (int kt = 0; kt < 4; ++kt)
#pragma unroll
                    for (int c = 0; c < 2; ++c)
                        Kn[kt][c] = *(const bf16x8*)
                            &Kb[(size_t)(k0 + 64 + kt * 16 + l16) * DK +
                                c * 32 + quad * 8];
            }

            if (k0 <= qbase + 31) {   // wave has live q rows for this tile
#pragma unroll
                for (int sub = 0; sub < 2; ++sub) {
                    f32x4 sT[4] = {};
#pragma unroll
                    for (int c = 0; c < 2; ++c)
#pragma unroll
                        for (int kt = 0; kt < 4; ++kt)
                            sT[kt] = __builtin_amdgcn_mfma_f32_16x16x32_bf16(
                                Kf[kt][c], Qf[sub][c], sT[kt], 0, 0, 0);

                    const int qg = qbase + sub * 16 + l16;
                    if (k0 + 63 > qbase + sub * 16) {   // causal mask needed
#pragma unroll
                        for (int kt = 0; kt < 4; ++kt)
#pragma unroll
                            for (int r = 0; r < 4; ++r)
                                if (k0 + kt * 16 + quad * 4 + r > qg)
                                    sT[kt][r] = -1e30f;
                    }

                    // online softmax, exp2 domain; defer-max (THR=8)
                    float tmax = -1e30f;
#pragma unroll
                    for (int kt = 0; kt < 4; ++kt)
#pragma unroll
                        for (int r = 0; r < 4; ++r)
                            tmax = fmaxf(tmax, sT[kt][r]);
                    tmax = fmaxf(tmax, __shfl_xor(tmax, 16));
                    tmax = fmaxf(tmax, __shfl_xor(tmax, 32));
                    if (!__all(tmax <= m_i[sub] + 8.0f)) {
                        float mnew = fmaxf(m_i[sub], tmax);
                        float alpha = exp2f(m_i[sub] - mnew);
                        m_i[sub] = mnew;
                        l_i[sub] *= alpha;
#pragma unroll
                        for (int dt = 0; dt < 4; ++dt) {
                            o[sub][dt][0] *= alpha; o[sub][dt][1] *= alpha;
                            o[sub][dt][2] *= alpha; o[sub][dt][3] *= alpha;
                        }
                    }
                    const float mn = m_i[sub];
                    float rs = 0.0f;
                    const int prow = wave * 32 + sub * 16 + l16;
#pragma unroll
                    for (int kt = 0; kt < 4; ++kt) {
                        float p0 = exp2f(sT[kt][0] - mn);
                        float p1 = exp2f(sT[kt][1] - mn);
                        float p2 = exp2f(sT[kt][2] - mn);
                        float p3 = exp2f(sT[kt][3] - mn);
                        rs += (p0 + p1) + (p2 + p3);
                        uint2 uu;
                        uu.x = cvt_pk_bf16(p0, p1);
                        uu.y = cvt_pk_bf16(p2, p3);
                        *(uint2*)&Ps[prow][kt * 16 + quad * 4] = uu;
                    }
                    rs += __shfl_xor(rs, 16);
                    rs += __shfl_xor(rs, 32);
                    l_i[sub] += rs;
                }

                // ---- O^T += V^T P^T ----
                bf16x8 Pf[2][2];
#pragma unroll
                for (int sub = 0; sub < 2; ++sub)
#pragma unroll
                    for (int c = 0; c < 2; ++c)
                        Pf[sub][c] = *(const bf16x8*)
                            &Ps[wave * 32 + sub * 16 + l16][c * 32 + quad * 8];
#pragma unroll
                for (int c = 0; c < 2; ++c)
#pragma unroll
                    for (int dt = 0; dt < 4; ++dt) {
                        bf16x8 av = *(const bf16x8*)
                            &Vt[buf][dt * 16 + l16][c * 32 + quad * 8];
#pragma unroll
                        for (int sub = 0; sub < 2; ++sub)
                            o[sub][dt] =
                                __builtin_amdgcn_mfma_f32_16x16x32_bf16(
                                    av, Pf[sub][c], o[sub][dt], 0, 0, 0);
                    }
            }

            if (need_next) {
#pragma unroll
                for (int kt = 0; kt < 4; ++kt)
#pragma unroll
                    for (int c = 0; c < 2; ++c)
                        Kf[kt][c] = Kn[kt][c];
            }
        }

        // ---- epilogue: normalize, write bf16 (b, s, d) ----
#pragma unroll
        for (int sub = 0; sub < 2; ++sub) {
            const int q = qbase + sub * 16 + l16;
            const float linv = 1.0f / l_i[sub];
            short* ob = &O[((size_t)bi * S_LEN + q) * D_MODEL + head * DK];
#pragma unroll
            for (int dt = 0; dt < 4; ++dt) {
                short4v h;
                h.x = f2bf(o[sub][dt][0] * linv);
                h.y = f2bf(o[sub][dt][1] * linv);
                h.z = f2bf(o[sub][dt][2] * linv);
                h.w = f2bf(o[sub][dt][3] * linv);
                *(short4v*)&ob[dt * 16 + quad * 4] = h;
            }
        }
    }
}

extern "C" void kernel_launch(void* const* d_in, const int* in_sizes, int n_in,
                              void* d_out, int out_size, void* d_ws, size_t ws_size,
                              hipStream_t stream) {
    const float* x  = (const float*)d_in[0];
    const float* Wq = (const float*)d_in[1];
    const float* Wk = (const float*)d_in[2];
    const float* Wv = (const float*)d_in[3];
    const float* Wo = (const float*)d_in[4];
    const int*   tp = (const int*)d_in[5];
    float* out = (float*)d_out;

    const int n  = BATCH * S_LEN * D_MODEL;       // 8388608
    const int nw = D_MODEL * D_MODEL;             // 1048576
    short* sw   = (short*)d_ws;
    short* xbf  = sw;
    short* Qbf  = sw + (size_t)n;
    short* Kbf  = sw + (size_t)2 * n;
    short* Vbf  = sw + (size_t)3 * n;
    short* Obf  = sw + (size_t)4 * n;
    short* Wqbf = sw + (size_t)5 * n;             // Wq;Wk;Wv contiguous (3072x1024)
    short* Wobf = Wqbf + (size_t)3 * nw;
    // RoPE table overlaid on Obf (dead until attn writes it; stream order
    // guarantees rope_tab -> proj_qkv(read) -> attn(overwrite) -> proj_out).
    float2* cst = (float2*)Obf;                   // 512 KB of the 16.8 MB region

    dim3 blk(256);
    conv_bf16<<<n / (256 * 8), blk, 0, stream>>>(x, xbf, n);
    dim3 gw(nw / (256 * 8), 4);
    conv_w4<<<gw, blk, 0, stream>>>(Wq, Wk, Wv, Wo, Wqbf);
    rope_tab<<<(S_LEN * 32) / 256, blk, 0, stream>>>(tp, cst);

    dim3 gqkv(3 * D_MODEL / 128, (BATCH * S_LEN) / 128);   // (24, 64)
    proj_qkv<<<gqkv, blk, 0, stream>>>(xbf, Wqbf, cst, Qbf, Kbf, Vbf);

    dim3 gattn(8, BATCH * NH);                             // paired causal
    attn_bf16<<<gattn, blk, 0, stream>>>(Qbf, Kbf, Vbf, Obf);

    dim3 gout(D_MODEL / 128, (BATCH * S_LEN) / 128);       // (8, 64)
    proj_out<<<gout, blk, 0, stream>>>(Obf, Wobf, out);
}

// Round 4
// 385.387 us; speedup vs baseline: 1.1074x; 1.0719x over previous
//
#include <hip/hip_runtime.h>
#include <math.h>

#define S_LEN 2048
#define D_MODEL 1024
#define NH 16
#define DK 64
#define BATCH 4

// log2(10000)/64
#define ROPE_L2F 0.20762050593046014f
// 0.125 * log2(e): folds 1/sqrt(dk) and exp->exp2 conversion into Q
#define QSCALE 0.18033688011112042f

typedef __attribute__((ext_vector_type(8))) short bf16x8;
typedef __attribute__((ext_vector_type(4))) short short4v;
typedef __attribute__((ext_vector_type(2))) short short2v;
typedef __attribute__((ext_vector_type(4))) float f32x4;

__device__ inline short f2bf(float f) {            // RNE fp32 -> bf16 bits
    unsigned u = __builtin_bit_cast(unsigned, f);
    unsigned r = u + 0x7FFFu + ((u >> 16) & 1u);
    return (short)(r >> 16);
}

// packed fp32x2 -> bf16x2 (RNE), single VALU op
__device__ inline unsigned cvt_pk_bf16(float lo, float hi) {
    unsigned r;
    asm("v_cvt_pk_bf16_f32 %0, %1, %2" : "=v"(r) : "v"(lo), "v"(hi));
    return r;
}

// async global->LDS, 16B per lane; lds base must be wave-uniform.
__device__ inline void load_lds16(const void* g, void* l) {
    __builtin_amdgcn_global_load_lds(
        (const __attribute__((address_space(1))) unsigned int*)g,
        (__attribute__((address_space(3))) unsigned int*)l, 16, 0, 0);
}

// ---------------------------------------------------------------------------
// One-time fp32 -> bf16 conversions.
// ---------------------------------------------------------------------------
__global__ __launch_bounds__(256) void conv_bf16(
    const float* __restrict__ src, short* __restrict__ dst, int n)
{
    int i = (blockIdx.x * 256 + threadIdx.x) * 8;
    if (i >= n) return;
    float4 a = *(const float4*)&src[i];
    float4 b = *(const float4*)&src[i + 4];
    short h[8] = { f2bf(a.x), f2bf(a.y), f2bf(a.z), f2bf(a.w),
                   f2bf(b.x), f2bf(b.y), f2bf(b.z), f2bf(b.w) };
    *(bf16x8*)&dst[i] = *(bf16x8*)h;
}

__global__ __launch_bounds__(256) void conv_w4(
    const float* __restrict__ Wq, const float* __restrict__ Wk,
    const float* __restrict__ Wv, const float* __restrict__ Wo,
    short* __restrict__ dst)
{
    const float* srcs[4] = { Wq, Wk, Wv, Wo };
    const float* s = srcs[blockIdx.y];
    short* d = dst + (size_t)blockIdx.y * (D_MODEL * D_MODEL);
    int i = (blockIdx.x * 256 + threadIdx.x) * 8;
    float4 a = *(const float4*)&s[i];
    float4 b = *(const float4*)&s[i + 4];
    short h[8] = { f2bf(a.x), f2bf(a.y), f2bf(a.z), f2bf(a.w),
                   f2bf(b.x), f2bf(b.y), f2bf(b.z), f2bf(b.w) };
    *(bf16x8*)&d[i] = *(bf16x8*)h;
}

// ---------------------------------------------------------------------------
// RoPE cos/sin table: cst[si*32 + f] = (cos, sin) of tp[si] * theta^(-2f/64).
// ---------------------------------------------------------------------------
__global__ __launch_bounds__(256) void rope_tab(
    const int* __restrict__ tp, float2* __restrict__ cst)
{
    int idx = blockIdx.x * 256 + threadIdx.x;      // 65536 entries
    int si = idx >> 5;
    int f  = idx & 31;
    float pos = (float)tp[si];
    float freq = exp2f(-(float)(2 * f) * ROPE_L2F);
    float s, c;
    __sincosf(pos * freq, &s, &c);
    cst[idx] = make_float2(c, s);
}

// ---------------------------------------------------------------------------
// bf16 MFMA GEMM main loop (m97-style): 128x128 tile, BK=32, 4 waves 2x2.
// A/B tiles staged via global_load_lds (16B/lane, async). LDS unpadded
// [128][32] shorts; 16B chunks XOR-swizzled (phys = chunk ^ (row&3)) so frag
// ds_read_b128 is <=4-way. Shared between proj_qkv and proj_out.
// ---------------------------------------------------------------------------
#define PROJ_PROLOGUE()                                                      \
    __shared__ short As[128][32];                                            \
    __shared__ short Bs[128][32];                                            \
    const int m0 = blockIdx.y * 128;                                         \
    const int n0 = blockIdx.x * 128;                                         \
    const int tid = threadIdx.x;                                             \
    const int lane = tid & 63;                                               \
    const int wave = tid >> 6;                                               \
    const int quad = lane >> 4;                                              \
    const int l16 = lane & 15;                                               \
    const int wr = (wave >> 1) * 64;                                         \
    const int wc = (wave & 1) * 64;                                          \
    const int srow = wave * 32 + (lane >> 2);                                \
    const int schunk = (lane & 3) ^ ((lane >> 2) & 3);                       \
    const short* agp = &A[(size_t)(m0 + srow) * D_MODEL + schunk * 8];       \
    const short* bgp = &Bw[(size_t)(n0 + srow) * D_MODEL + schunk * 8];      \
    short* alds0 = &As[wave * 32][0];                                        \
    short* alds1 = &As[wave * 32 + 16][0];                                   \
    short* blds0 = &Bs[wave * 32][0];                                        \
    short* blds1 = &Bs[wave * 32 + 16][0];                                   \
    const int fchunk = quad ^ (l16 & 3);                                     \
    f32x4 acc[4][4] = {};                                                    \
    for (int k0 = 0; k0 < D_MODEL; k0 += 32) {                               \
        load_lds16(agp, alds0);                                              \
        load_lds16(agp + 16 * D_MODEL, alds1);                               \
        load_lds16(bgp, blds0);                                              \
        load_lds16(bgp + 16 * D_MODEL, blds1);                               \
        agp += 32; bgp += 32;                                                \
        __syncthreads();                                                     \
        bf16x8 a_h[4], b_h[4];                                               \
        _Pragma("unroll")                                                    \
        for (int t = 0; t < 4; ++t) {                                        \
            a_h[t] = *(const bf16x8*)&As[wr + t * 16 + l16][fchunk * 8];     \
            b_h[t] = *(const bf16x8*)&Bs[wc + t * 16 + l16][fchunk * 8];     \
        }                                                                    \
        _Pragma("unroll")                                                    \
        for (int mt = 0; mt < 4; ++mt)                                       \
            _Pragma("unroll")                                                \
            for (int nt = 0; nt < 4; ++nt)                                   \
                acc[mt][nt] = __builtin_amdgcn_mfma_f32_16x16x32_bf16(       \
                    a_h[mt], b_h[nt], acc[mt][nt], 0, 0, 0);                 \
        __syncthreads();                                                     \
    }

// ---------------------------------------------------------------------------
// Fused QKV projection: C = x (8192x1024) @ [Wq;Wk;Wv]^T (1024x3072).
// ---------------------------------------------------------------------------
__global__ __launch_bounds__(256) void proj_qkv(
    const short* __restrict__ A, const short* __restrict__ Bw,
    const float2* __restrict__ cst,
    short* __restrict__ Qo, short* __restrict__ Ko, short* __restrict__ Vo)
{
    PROJ_PROLOGUE()

    const int which = n0 >> 10;                    // 0=Q 1=K 2=V
    short* __restrict__ outp = (which == 0) ? Qo : (which == 1) ? Ko : Vo;
    const float scale = (which == 0) ? QSCALE : 1.0f;
    const int nbase = n0 & (D_MODEL - 1);

#pragma unroll
    for (int mt = 0; mt < 4; ++mt) {
#pragma unroll
        for (int r = 0; r < 4; ++r) {
            const int row = m0 + wr + mt * 16 + quad * 4 + r;
            const int bi = row >> 11;
            const int si = row & (S_LEN - 1);
#pragma unroll
            for (int nt = 0; nt < 4; ++nt) {
                const int col = nbase + wc + nt * 16 + l16;
                const int head = col >> 6;
                const int tloc = col & 63;
                float v = acc[mt][nt][r];
                float res;
                if (which < 2) {
                    float partner = __shfl_xor(v, 1);
                    float xe = (lane & 1) ? partner : v;
                    float xo = (lane & 1) ? v : partner;
                    float2 cs = cst[si * 32 + (tloc >> 1)];
                    res = ((lane & 1) ? (cs.y * xe + cs.x * xo)
                                      : (cs.x * xe - cs.y * xo)) * scale;
                } else {
                    res = v;
                }
                outp[(((size_t)bi * NH + head) * S_LEN + si) * DK + tloc] =
                    f2bf(res);
            }
        }
    }
}

// ---------------------------------------------------------------------------
// Output projection: out = attnO (8192x1024) @ Wo^T, fp32 row-major.
// ---------------------------------------------------------------------------
__global__ __launch_bounds__(256) void proj_out(
    const short* __restrict__ A, const short* __restrict__ Bw,
    float* __restrict__ outf)
{
    PROJ_PROLOGUE()

#pragma unroll
    for (int mt = 0; mt < 4; ++mt) {
#pragma unroll
        for (int r = 0; r < 4; ++r) {
            const int row = m0 + wr + mt * 16 + quad * 4 + r;
#pragma unroll
            for (int nt = 0; nt < 4; ++nt) {
                int col = n0 + wc + nt * 16 + l16;
                outf[(size_t)row * D_MODEL + col] = acc[mt][nt][r];
            }
        }
    }
}

// ---------------------------------------------------------------------------
// MFMA flash causal attention — latency-path-optimized.
// Round-3 counters: MfmaUtil 7.8 / VALUBusy 32 / HBM 3% / Occ 11% =>
// latency-bound on the per-tile serial chain (2 waves/SIMD can't hide it).
// Changes vs round-3:
//  * ONE barrier per TWO k-tiles: Vt is 4-deep (two dbuf pairs); commit
//    tiles (t,t+1), sync once, compute both. Waves drift a full 2-tile
//    window => cross-wave MFMA/VALU overlap (m114).
//  * Softmax common path has ZERO cross-lane ops: l_i kept lane-partial
//    (reduced once in epilogue); defer-max checked via __all on the
//    per-lane max (ballot, no shuffle) — tmax reduce+rescale only on the
//    rare (~once/q-tile) violation path.
//  * K frags prefetch directly into Kf[parity] right after last use (WAR).
// Kept: balanced pairing (34 tiles/block uniform), XCD head-grouping
// (FETCH 110->24.7 MB), defer-max THR=8, cvt_pk P-packing, no setprio.
// Cross-half / cross-iteration buffer safety: barrier after each half's
// k-loop; within the loop, iter i writes bufs {2(i&1), 2(i&1)+1} while a
// one-barrier-behind wave reads the other pair.
// ---------------------------------------------------------------------------
#define PADS 72

__global__ __launch_bounds__(256) void attn_bf16(
    const short* __restrict__ Q, const short* __restrict__ K,
    const short* __restrict__ V, short* __restrict__ O)
{
    __shared__ short Vt[4][64][PADS];  // V tiles transposed [d][k], 2 dbuf pairs
    __shared__ short Ps[128][PADS];    // P rows, wave-private

    const int bh   = blockIdx.x * 8 + (blockIdx.y >> 3);
    const int pair = blockIdx.y & 7;

    const int tid = threadIdx.x;
    const int wave = tid >> 6;
    const int lane = tid & 63;
    const int quad = lane >> 4;
    const int l16 = lane & 15;

    const short* Kb = K + (size_t)bh * S_LEN * DK;
    const short* Vb = V + (size_t)bh * S_LEN * DK;

    // V staging geometry (transpose via short2)
    const int kp2 = (tid & 31) * 2;
    const int db = (tid >> 5) * 8;

    const int bi = bh >> 4;
    const int head = bh & 15;

    for (int half = 0; half < 2; ++half) {
        const int bx = half ? pair : (15 - pair);
        const int qbase = bx * 128 + wave * 32;
        const int qlim = qbase + 31;

        // Q fragments straight from global (wave-private rows)
        bf16x8 Qf[2][2];
#pragma unroll
        for (int sub = 0; sub < 2; ++sub)
#pragma unroll
            for (int c = 0; c < 2; ++c)
                Qf[sub][c] = *(const bf16x8*)
                    &Q[((size_t)bh * S_LEN + qbase + sub * 16 + l16) * DK +
                       c * 32 + quad * 8];

        // preload tiles 0,1: V rows into regs, K frags into regs
        bf16x8 va0 = *(const bf16x8*)&Vb[(size_t)kp2 * DK + db];
        bf16x8 va1 = *(const bf16x8*)&Vb[(size_t)(kp2 + 1) * DK + db];
        bf16x8 vb0 = *(const bf16x8*)&Vb[(size_t)(64 + kp2) * DK + db];
        bf16x8 vb1 = *(const bf16x8*)&Vb[(size_t)(64 + kp2 + 1) * DK + db];
        bf16x8 Kf[2][4][2];   // [tile parity][kt][c]
#pragma unroll
        for (int par = 0; par < 2; ++par)
#pragma unroll
            for (int kt = 0; kt < 4; ++kt)
#pragma unroll
                for (int c = 0; c < 2; ++c)
                    Kf[par][kt][c] = *(const bf16x8*)
                        &Kb[(size_t)(par * 64 + kt * 16 + l16) * DK +
                            c * 32 + quad * 8];

        float m_i[2] = { -1e30f, -1e30f };
        float l_i[2] = { 0.0f, 0.0f };     // LANE-PARTIAL; reduced in epilogue
        f32x4 o[2][4] = {};

        const int ktiles = 2 * bx + 2;     // always even
        for (int tt = 0; tt < ktiles; tt += 2) {
            const int bufA = (tt & 2);     // {0,2,0,2,...}
            const int bufB = bufA | 1;

            // ---- commit both prefetched V tiles ----
#pragma unroll
            for (int i = 0; i < 8; ++i) {
                short2v pa; pa.x = va0[i]; pa.y = va1[i];
                *(short2v*)&Vt[bufA][db + i][kp2] = pa;
                short2v pb; pb.x = vb0[i]; pb.y = vb1[i];
                *(short2v*)&Vt[bufB][db + i][kp2] = pb;
            }
            __syncthreads();               // one barrier per 2 tiles

            // ---- prefetch V tiles tt+2, tt+3 ----
            if (tt + 2 < ktiles) {
                const short* vp = &Vb[(size_t)((tt + 2) * 64 + kp2) * DK + db];
                va0 = *(const bf16x8*)vp;
                va1 = *(const bf16x8*)(vp + DK);
                vp += (size_t)64 * DK;
                vb0 = *(const bf16x8*)vp;
                vb1 = *(const bf16x8*)(vp + DK);
            }

            // ================= two tiles =================
#pragma unroll
            for (int sel = 0; sel < 2; ++sel) {
                const int t  = tt + sel;
                const int k0 = t * 64;
                const int buf = sel ? bufB : bufA;
                if (k0 > qlim) continue;   // wave has no live q rows here

                // ---- S^T = K * Q^T ----
                f32x4 sT2[2][4];
#pragma unroll
                for (int sub = 0; sub < 2; ++sub) {
#pragma unroll
                    for (int kt = 0; kt < 4; ++kt) sT2[sub][kt] = f32x4{};
#pragma unroll
                    for (int c = 0; c < 2; ++c)
#pragma unroll
                        for (int kt = 0; kt < 4; ++kt)
                            sT2[sub][kt] =
                                __builtin_amdgcn_mfma_f32_16x16x32_bf16(
                                    Kf[sel][kt][c], Qf[sub][c],
                                    sT2[sub][kt], 0, 0, 0);
                }

                // Kf[sel] dead now -> prefetch tile t+2 into it (WAR)
                if (k0 + 128 <= qlim) {
#pragma unroll
                    for (int kt = 0; kt < 4; ++kt)
#pragma unroll
                        for (int c = 0; c < 2; ++c)
                            Kf[sel][kt][c] = *(const bf16x8*)
                                &Kb[(size_t)(k0 + 128 + kt * 16 + l16) * DK +
                                    c * 32 + quad * 8];
                }

#pragma unroll
                for (int sub = 0; sub < 2; ++sub) {
                    f32x4* sT = sT2[sub];
                    const int qg = qbase + sub * 16 + l16;
                    if (k0 + 63 > qbase + sub * 16) {   // causal mask needed
#pragma unroll
                        for (int kt = 0; kt < 4; ++kt)
#pragma unroll
                            for (int r = 0; r < 4; ++r)
                                if (k0 + kt * 16 + quad * 4 + r > qg)
                                    sT[kt][r] = -1e30f;
                    }

                    // per-lane max (no cross-lane in common path)
                    float tmax = fmaxf(
                        fmaxf(fmaxf(sT[0][0], sT[0][1]),
                              fmaxf(sT[0][2], sT[0][3])),
                        fmaxf(fmaxf(fmaxf(sT[1][0], sT[1][1]),
                                    fmaxf(sT[1][2], sT[1][3])),
                              fmaxf(fmaxf(fmaxf(sT[2][0], sT[2][1]),
                                          fmaxf(sT[2][2], sT[2][3])),
                                    fmaxf(fmaxf(sT[3][0], sT[3][1]),
                                          fmaxf(sT[3][2], sT[3][3])))));
                    // defer-max: rescale only if some lane exceeds m+8
                    if (!__all(tmax <= m_i[sub] + 8.0f)) {
                        float tm = fmaxf(tmax, __shfl_xor(tmax, 16));
                        tm = fmaxf(tm, __shfl_xor(tm, 32));
                        float mnew = fmaxf(m_i[sub], tm);
                        float alpha = exp2f(m_i[sub] - mnew);
                        m_i[sub] = mnew;
                        l_i[sub] *= alpha;
#pragma unroll
                        for (int dt = 0; dt < 4; ++dt) {
                            o[sub][dt][0] *= alpha; o[sub][dt][1] *= alpha;
                            o[sub][dt][2] *= alpha; o[sub][dt][3] *= alpha;
                        }
                    }
                    const float mn = m_i[sub];
                    float rs = 0.0f;
                    const int prow = wave * 32 + sub * 16 + l16;
#pragma unroll
                    for (int kt = 0; kt < 4; ++kt) {
                        float p0 = exp2f(sT[kt][0] - mn);
                        float p1 = exp2f(sT[kt][1] - mn);
                        float p2 = exp2f(sT[kt][2] - mn);
                        float p3 = exp2f(sT[kt][3] - mn);
                        rs += (p0 + p1) + (p2 + p3);
                        uint2 uu;
                        uu.x = cvt_pk_bf16(p0, p1);
                        uu.y = cvt_pk_bf16(p2, p3);
                        *(uint2*)&Ps[prow][kt * 16 + quad * 4] = uu;
                    }
                    l_i[sub] += rs;        // lane-partial accumulate
                }

                // ---- O^T += V^T P^T ----
                bf16x8 Pf[2][2];
#pragma unroll
                for (int sub = 0; sub < 2; ++sub)
#pragma unroll
                    for (int c = 0; c < 2; ++c)
                        Pf[sub][c] = *(const bf16x8*)
                            &Ps[wave * 32 + sub * 16 + l16][c * 32 + quad * 8];
#pragma unroll
                for (int c = 0; c < 2; ++c)
#pragma unroll
                    for (int dt = 0; dt < 4; ++dt) {
                        bf16x8 av = *(const bf16x8*)
                            &Vt[buf][dt * 16 + l16][c * 32 + quad * 8];
#pragma unroll
                        for (int sub = 0; sub < 2; ++sub)
                            o[sub][dt] =
                                __builtin_amdgcn_mfma_f32_16x16x32_bf16(
                                    av, Pf[sub][c], o[sub][dt], 0, 0, 0);
                    }
            }
        }
        __syncthreads();   // protect Vt bufs before next half's first commit

        // ---- epilogue: reduce lane-partial l, normalize, write bf16 ----
#pragma unroll
        for (int sub = 0; sub < 2; ++sub) {
            float lt = l_i[sub];
            lt += __shfl_xor(lt, 16);
            lt += __shfl_xor(lt, 32);
            const float linv = 1.0f / lt;
            const int q = qbase + sub * 16 + l16;
            short* ob = &O[((size_t)bi * S_LEN + q) * D_MODEL + head * DK];
#pragma unroll
            for (int dt = 0; dt < 4; ++dt) {
                short4v h;
                h.x = f2bf(o[sub][dt][0] * linv);
                h.y = f2bf(o[sub][dt][1] * linv);
                h.z = f2bf(o[sub][dt][2] * linv);
                h.w = f2bf(o[sub][dt][3] * linv);
                *(short4v*)&ob[dt * 16 + quad * 4] = h;
            }
        }
    }
}

extern "C" void kernel_launch(void* const* d_in, const int* in_sizes, int n_in,
                              void* d_out, int out_size, void* d_ws, size_t ws_size,
                              hipStream_t stream) {
    const float* x  = (const float*)d_in[0];
    const float* Wq = (const float*)d_in[1];
    const float* Wk = (const float*)d_in[2];
    const float* Wv = (const float*)d_in[3];
    const float* Wo = (const float*)d_in[4];
    const int*   tp = (const int*)d_in[5];
    float* out = (float*)d_out;

    const int n  = BATCH * S_LEN * D_MODEL;       // 8388608
    const int nw = D_MODEL * D_MODEL;             // 1048576
    short* sw   = (short*)d_ws;
    short* xbf  = sw;
    short* Qbf  = sw + (size_t)n;
    short* Kbf  = sw + (size_t)2 * n;
    short* Vbf  = sw + (size_t)3 * n;
    short* Obf  = sw + (size_t)4 * n;
    short* Wqbf = sw + (size_t)5 * n;             // Wq;Wk;Wv contiguous (3072x1024)
    short* Wobf = Wqbf + (size_t)3 * nw;
    // RoPE table overlaid on Obf (dead until attn writes it; stream order
    // guarantees rope_tab -> proj_qkv(read) -> attn(overwrite) -> proj_out).
    float2* cst = (float2*)Obf;                   // 512 KB of the 16.8 MB region

    dim3 blk(256);
    conv_bf16<<<n / (256 * 8), blk, 0, stream>>>(x, xbf, n);
    dim3 gw(nw / (256 * 8), 4);
    conv_w4<<<gw, blk, 0, stream>>>(Wq, Wk, Wv, Wo, Wqbf);
    rope_tab<<<(S_LEN * 32) / 256, blk, 0, stream>>>(tp, cst);

    dim3 gqkv(3 * D_MODEL / 128, (BATCH * S_LEN) / 128);   // (24, 64)
    proj_qkv<<<gqkv, blk, 0, stream>>>(xbf, Wqbf, cst, Qbf, Kbf, Vbf);

    dim3 gattn(8, BATCH * NH);                             // paired causal
    attn_bf16<<<gattn, blk, 0, stream>>>(Qbf, Kbf, Vbf, Obf);

    dim3 gout(D_MODEL / 128, (BATCH * S_LEN) / 128);       // (8, 64)
    proj_out<<<gout, blk, 0, stream>>>(Obf, Wobf, out);
}